// Round 2
// baseline (4293.548 us; speedup 1.0000x reference)
//
#include <hip/hip_runtime.h>
#include <stdint.h>

typedef __attribute__((ext_vector_type(4))) int   i32x4;
typedef __attribute__((ext_vector_type(8))) short bf16x8;
typedef __attribute__((ext_vector_type(4))) float f32x4;

#define DEV static __device__ __forceinline__

constexpr int  kB = 128, kT = 512, kD = 512, kH = 512;
constexpr int  kGC = 2048;               // 4*H
constexpr int  ROWS = 32;                // batch rows per block
constexpr int  NG = 4;                   // batch groups
constexpr int  NJ = 32;                  // column-slice blocks per cluster
constexpr int  NTHREADS = 512;
constexpr size_t SLOT_ELEMS = (size_t)kB * kH;            // bf16 elems per ring slot -> 128 KB
constexpr size_t WIMG_ELEMS = (size_t)2 * NJ * 4 * 32 * 512; // 4,194,304 bf16
constexpr size_t WIMG_BYTES = WIMG_ELEMS * 2;             // 8 MB
constexpr int  RFULL = kT + 1;           // 513
constexpr int  FLAG_STRIDE = 256;        // bytes per (l,g,t): 32 j x 8 waves, 1 byte each
constexpr size_t FLAG_TOTAL = (size_t)2 * NG * kT * FLAG_STRIDE; // 1 MB

DEV ushort f2bf(float f) {
  uint32_t u = __float_as_uint(f);
  u += 0x7fff + ((u >> 16) & 1);        // round-to-nearest-even
  return (ushort)(u >> 16);
}
DEV int pk2(float a, float b) { return (int)((uint32_t)f2bf(a) | ((uint32_t)f2bf(b) << 16)); }
DEV float sigf(float v)  { return 1.f / (1.f + __expf(-v)); }
DEV float tanhf_(float v){ return 1.f - 2.f / (__expf(2.f * v) + 1.f); }

// ---- prep: W (L,1024,2048) fp32 -> bf16 MFMA B-fragment image ----
__global__ void prep_w(const float* __restrict__ W, ushort* __restrict__ wimg) {
  uint32_t idx = blockIdx.x * 256u + threadIdx.x;
  int e = idx & 7, lane = (idx >> 3) & 63, ks = (idx >> 9) & 31;
  int G = (idx >> 14) & 3, j = (idx >> 16) & 31, l = (idx >> 21) & 1;
  int k = ks * 32 + ((lane >> 4) << 3) + e;
  int c = G * 512 + j * 16 + (lane & 15);
  wimg[idx] = f2bf(W[(size_t)l * 1024 * 2048 + (size_t)k * 2048 + c]);
}

// ---- prep: initial h (hiddens[l][0]) fp32 -> ring slot 0 bf16 ----
__global__ void prep_init(const float* __restrict__ hiddens, ushort* __restrict__ r0, ushort* __restrict__ r1) {
  uint32_t idx = blockIdx.x * 256u + threadIdx.x;   // 0 .. 2*65536-1
  int l = idx >> 16; uint32_t r = idx & 65535u;
  ushort v = f2bf(hiddens[(size_t)(l * 2 + 0) * 65536 + r]);
  (l ? r1 : r0)[r] = v;
}

// Poll a 256-byte flag region: lane L owns dword L, spins until its 4 bytes set.
// Signal path only — 4 cachelines per wave per iteration, agent-scope (L1-bypassing).
DEV void poll_flags(const uint8_t* fb, int lane) {
  const uint32_t* p = reinterpret_cast<const uint32_t*>(fb) + lane;
  while (__hip_atomic_load(p, __ATOMIC_RELAXED, __HIP_MEMORY_SCOPE_AGENT) != 0x01010101u)
    __builtin_amdgcn_s_sleep(1);
}

// Bulk-stage 32 rows x 512 cols bf16 from a ring slot into a swizzled LDS half-tile.
// PLAIN vector loads (fast path): validity is guaranteed by a prior poll_flags,
// addresses are first-touch per run (write-once slots + entry threadfence).
DEV void stage_h(ushort* Ab, const ushort* rbase, int g, int tid) {
  #pragma unroll
  for (int p = 0; p < 4; ++p) {
    int o = (tid + p * NTHREADS) * 16, row = o >> 10, kb = o & 1023;
    i32x4 v = *reinterpret_cast<const i32x4*>(rbase + (size_t)(g * ROWS + row) * kH + (kb >> 1));
    *reinterpret_cast<i32x4*>(reinterpret_cast<char*>(Ab) + ((row * 1024 + kb) ^ ((row & 7) << 4))) = v;
  }
}

// ======================= BIG path: per-wave single-writer flags =======================
__launch_bounds__(NTHREADS, 2)
__global__ void lstm_flag(const float* __restrict__ x, const float* __restrict__ hiddens,
                          const float* __restrict__ bias, const ushort* __restrict__ wimg,
                          ushort* __restrict__ ring0, ushort* __restrict__ ring1,
                          uint8_t* __restrict__ flags, float* __restrict__ out) {
  __shared__ ushort AbufX[ROWS * 512];    // 32 KB: input half (k=0..511)
  __shared__ ushort AbufH[ROWS * 512];    // 32 KB: recurrent half (k=512..1023)
  __shared__ float  gbuf[4][ROWS][17];    // activated gates i,f,g,o (+1 pad: kills 4-way write conflict)

  const int tid  = threadIdx.x;
  const int lane = tid & 63;
  const int wv   = tid >> 6;
  const int G    = wv & 3;                // gate strip
  const int rf   = wv >> 2;               // row-fragment (16 rows)
  const int j    = blockIdx.x & 31;       // column slice
  const int g    = (blockIdx.x >> 5) & 3; // batch group
  const int l    = blockIdx.x >> 7;       // layer

  __threadfence();  // entry agent fence: kill cross-replay stale cache lines

  // W slice resident in registers: 32 ksteps x 16B B-fragments
  i32x4 wr[32];
  {
    const ushort* base = wimg + (((size_t)(l * NJ + j) * 4 + G) * 32) * 512 + lane * 8;
    #pragma unroll
    for (int ks = 0; ks < 32; ++ks)
      wr[ks] = *reinterpret_cast<const i32x4*>(base + ks * 512);
  }
  const float bval = bias[l * kGC + G * 512 + j * 16 + (lane & 15)];
  const int urow = tid >> 4, ucol = tid & 15;        // c/h-update role
  float creg = hiddens[((size_t)(l * 2 + 1) * kB + (g * ROWS + urow)) * kH + j * 16 + ucol];

  ushort* rrec = l ? ring1 : ring0;
  uint8_t* myflags = flags + (size_t)(l * NG + g) * kT * FLAG_STRIDE;
  const uint8_t* xflags = flags + (size_t)(0 * NG + g) * kT * FLAG_STRIDE;  // layer0 cluster (l==1 only)

  const int arow  = rf * 16 + (lane & 15);
  const int koff  = (lane >> 4) << 3;
  const int abase = arow * 1024;
  const int aswz  = (arow & 7) << 4;

  for (int t = 0; t < kT; ++t) {
    // ---------- phase A: input half -> AbufX ----------
    if (l == 1) {
      poll_flags(xflags + (size_t)t * FLAG_STRIDE, lane);      // layer0 finished step t
      stage_h(AbufX, ring0 + (size_t)(t + 1) * SLOT_ELEMS, g, tid);
    } else {
      #pragma unroll
      for (int p = 0; p < 4; ++p) {
        int o = (tid + p * NTHREADS) * 16, row = o >> 10, kb = o & 1023;
        const float* src = x + ((size_t)(g * ROWS + row) * kT + t) * kD + (kb >> 1);
        f32x4 f0 = *reinterpret_cast<const f32x4*>(src);
        f32x4 f1 = *reinterpret_cast<const f32x4*>(src + 4);
        i32x4 v;
        v[0] = pk2(f0[0], f0[1]); v[1] = pk2(f0[2], f0[3]);
        v[2] = pk2(f1[0], f1[1]); v[3] = pk2(f1[2], f1[3]);
        *reinterpret_cast<i32x4*>(reinterpret_cast<char*>(AbufX) + ((row * 1024 + kb) ^ ((row & 7) << 4))) = v;
      }
    }
    // ---------- phase B: recurrent half -> AbufH ----------
    if (t > 0) poll_flags(myflags + (size_t)(t - 1) * FLAG_STRIDE, lane);
    stage_h(AbufH, rrec + (size_t)t * SLOT_ELEMS, g, tid);
    __syncthreads();                                   // S1: both A halves ready

    // ---------- full K=1024 MFMA ----------
    f32x4 acc = {};
    #pragma unroll
    for (int ks = 0; ks < 16; ++ks) {
      int off = (abase + ((ks * 32 + koff) << 1)) ^ aswz;
      i32x4 av = *reinterpret_cast<const i32x4*>(reinterpret_cast<const char*>(AbufX) + off);
      acc = __builtin_amdgcn_mfma_f32_16x16x32_bf16(
              *reinterpret_cast<bf16x8*>(&av), *reinterpret_cast<bf16x8*>(&wr[ks]), acc, 0, 0, 0);
    }
    #pragma unroll
    for (int ks = 0; ks < 16; ++ks) {
      int off = (abase + ((ks * 32 + koff) << 1)) ^ aswz;
      i32x4 av = *reinterpret_cast<const i32x4*>(reinterpret_cast<const char*>(AbufH) + off);
      acc = __builtin_amdgcn_mfma_f32_16x16x32_bf16(
              *reinterpret_cast<bf16x8*>(&av), *reinterpret_cast<bf16x8*>(&wr[16 + ks]), acc, 0, 0, 0);
    }

    // ---------- activation + gate exchange ----------
    #pragma unroll
    for (int q = 0; q < 4; ++q) {
      float v2 = acc[q] + bval;
      v2 = (G == 2) ? tanhf_(v2) : sigf(v2);
      gbuf[G][rf * 16 + ((lane >> 4) << 2) + q][lane & 15] = v2;  // C/D: row=(lane>>4)*4+q, col=lane&15
    }
    __syncthreads();                                   // S2: gates ready

    // ---------- c/h update, publish, per-wave flag ----------
    {
      float iv = gbuf[0][urow][ucol], fv = gbuf[1][urow][ucol];
      float gv = gbuf[2][urow][ucol], ov = gbuf[3][urow][ucol];
      creg = fv * creg + iv * gv;
      float hh = ov * tanhf_(creg);
      int b = g * ROWS + urow;
      uint32_t me    = f2bf(hh);
      uint32_t other = (uint32_t)__shfl_xor((int)me, 1);  // partner col^1, same wave
      if (!(ucol & 1)) {
        uint32_t pkv = me | (other << 16);
        uint32_t* dst = (uint32_t*)(rrec + (size_t)(t + 1) * SLOT_ELEMS
                                    + (size_t)b * kH + j * 16 + ucol);
        __hip_atomic_store(dst, pkv, __ATOMIC_RELAXED, __HIP_MEMORY_SCOPE_AGENT);
      }
      // drain THIS wave's publish stores, then set THIS wave's flag byte.
      // No cross-wave barrier needed: flag granularity == this wave's 4 rows.
      asm volatile("s_waitcnt vmcnt(0)" ::: "memory");
      if (lane == 0)
        __hip_atomic_store(myflags + (size_t)t * FLAG_STRIDE + j * 8 + wv, (uint8_t)1,
                           __ATOMIC_RELAXED, __HIP_MEMORY_SCOPE_AGENT);
      // bulk output writes AFTER the flag: they don't delay the signal
      if (l == 1) out[((size_t)b * kT + t) * kH + j * 16 + ucol] = hh;
      if (t == kT - 1) {
        size_t hb = (size_t)kB * kT * kH;
        out[hb + ((size_t)(l * 2 + 0) * kB + b) * kH + j * 16 + ucol] = hh;
        out[hb + ((size_t)(l * 2 + 1) * kB + b) * kH + j * 16 + ucol] = creg;
      }
    }
    // no 3rd barrier: next S1 orders gbuf/Abuf reuse (all reads of step t precede S2)
  }
}

// ======================= small-workspace fallback (round-0 proven path) =======================

template<bool BIG>
DEV void stage_ring(ushort* Abuf_, const ushort* rbase, int g, int tid) {
  #pragma unroll
  for (int p = 0; p < 4; ++p) {
    int o = (tid + p * NTHREADS) * 16;
    int row = o >> 10, kb = o & 1023;
    const ushort* src = rbase + (size_t)(g * ROWS + row) * kH + (kb >> 1);
    i32x4 v;
    if (BIG) {
      v = *reinterpret_cast<const i32x4*>(src);
    } else {
      uint64_t lo = __hip_atomic_load((const uint64_t*)src,       __ATOMIC_RELAXED, __HIP_MEMORY_SCOPE_AGENT);
      uint64_t hi = __hip_atomic_load((const uint64_t*)(src + 4), __ATOMIC_RELAXED, __HIP_MEMORY_SCOPE_AGENT);
      v[0] = (int)(uint32_t)lo; v[1] = (int)(uint32_t)(lo >> 32);
      v[2] = (int)(uint32_t)hi; v[3] = (int)(uint32_t)(hi >> 32);
    }
    *reinterpret_cast<i32x4*>(reinterpret_cast<char*>(Abuf_) + ((row * 1024 + kb) ^ ((row & 7) << 4))) = v;
  }
}

template<bool BIG>
__launch_bounds__(NTHREADS, 2)
__global__ void lstm_main(const float* __restrict__ x, const float* __restrict__ hiddens,
                          const float* __restrict__ bias, const ushort* __restrict__ wimg,
                          ushort* __restrict__ ring0, ushort* __restrict__ ring1,
                          int* __restrict__ cnt, int* __restrict__ cons0,
                          float* __restrict__ out, int R0, int R1) {
  __shared__ ushort Abuf[ROWS * 512];
  __shared__ float  gbuf[4][ROWS][16];
  __shared__ float  cbuf[ROWS][16];
  __shared__ float  hbuf[ROWS][16];

  const int tid  = threadIdx.x;
  const int lane = tid & 63;
  const int wv   = tid >> 6;
  const int G    = wv & 3;
  const int rf   = wv >> 2;
  const int j    = blockIdx.x & 31;
  const int g    = (blockIdx.x >> 5) & 3;
  const int l    = blockIdx.x >> 7;

  __threadfence();

  i32x4 wr[32];
  {
    const ushort* base = wimg + (((size_t)(l * NJ + j) * 4 + G) * 32) * 512 + lane * 8;
    #pragma unroll
    for (int ks = 0; ks < 32; ++ks)
      wr[ks] = *reinterpret_cast<const i32x4*>(base + ks * 512);
  }
  const float bval = bias[l * kGC + G * 512 + j * 16 + (lane & 15)];
  {
    int row = tid >> 4, col = tid & 15;
    cbuf[row][col] = hiddens[((size_t)(l * 2 + 1) * kB + (g * ROWS + row)) * kH + j * 16 + col];
  }
  int* mycnt = cnt + (l * NG + g) * kT;
  int* c0cnt = cnt + g * kT;
  ushort* rrec = l ? ring1 : ring0;
  const int Rrec = l ? R1 : R0;

  const int arow  = rf * 16 + (lane & 15);
  const int koff  = (lane >> 4) << 3;
  const int abase = arow * 1024;
  const int aswz  = (arow & 7) << 4;

  __syncthreads();

  for (int t = 0; t < kT; ++t) {
    if (l == 1) {
      if (tid == 0) {
        while (__hip_atomic_load(&c0cnt[t], __ATOMIC_RELAXED, __HIP_MEMORY_SCOPE_AGENT) < NJ)
          __builtin_amdgcn_s_sleep(2);
      }
      __syncthreads();
      stage_ring<BIG>(Abuf, ring0 + (size_t)((t + 1) % R0) * SLOT_ELEMS, g, tid);
    } else {
      #pragma unroll
      for (int p = 0; p < 4; ++p) {
        int o = (tid + p * NTHREADS) * 16;
        int row = o >> 10, kb = o & 1023;
        const float* src = x + ((size_t)(g * ROWS + row) * kT + t) * kD + (kb >> 1);
        f32x4 f0 = *reinterpret_cast<const f32x4*>(src);
        f32x4 f1 = *reinterpret_cast<const f32x4*>(src + 4);
        i32x4 v;
        v[0] = pk2(f0[0], f0[1]); v[1] = pk2(f0[2], f0[3]);
        v[2] = pk2(f1[0], f1[1]); v[3] = pk2(f1[2], f1[3]);
        *reinterpret_cast<i32x4*>(reinterpret_cast<char*>(Abuf) + ((row * 1024 + kb) ^ ((row & 7) << 4))) = v;
      }
    }
    __syncthreads();
    if (!BIG && l == 1 && tid == 0)
      __hip_atomic_fetch_add(&cons0[g * kT + t], 1, __ATOMIC_RELAXED, __HIP_MEMORY_SCOPE_AGENT);

    f32x4 acc = {};
    #pragma unroll
    for (int ks = 0; ks < 16; ++ks) {
      int off = (abase + ((ks * 32 + koff) << 1)) ^ aswz;
      i32x4 av = *reinterpret_cast<const i32x4*>(reinterpret_cast<const char*>(Abuf) + off);
      acc = __builtin_amdgcn_mfma_f32_16x16x32_bf16(
              *reinterpret_cast<bf16x8*>(&av), *reinterpret_cast<bf16x8*>(&wr[ks]), acc, 0, 0, 0);
    }
    __syncthreads();

    if (t > 0) {
      if (tid == 0) {
        while (__hip_atomic_load(&mycnt[t - 1], __ATOMIC_RELAXED, __HIP_MEMORY_SCOPE_AGENT) < NJ)
          __builtin_amdgcn_s_sleep(2);
        if (!BIG && l == 0 && t >= R0) {
          while (__hip_atomic_load(&cons0[g * kT + (t - R0)], __ATOMIC_RELAXED, __HIP_MEMORY_SCOPE_AGENT) < NJ)
            __builtin_amdgcn_s_sleep(2);
        }
      }
      __syncthreads();
    }
    stage_ring<BIG>(Abuf, rrec + (size_t)(t % Rrec) * SLOT_ELEMS, g, tid);
    __syncthreads();

    #pragma unroll
    for (int ks = 0; ks < 16; ++ks) {
      int off = (abase + ((ks * 32 + koff) << 1)) ^ aswz;
      i32x4 av = *reinterpret_cast<const i32x4*>(reinterpret_cast<const char*>(Abuf) + off);
      acc = __builtin_amdgcn_mfma_f32_16x16x32_bf16(
              *reinterpret_cast<bf16x8*>(&av), *reinterpret_cast<bf16x8*>(&wr[16 + ks]), acc, 0, 0, 0);
    }

    #pragma unroll
    for (int q = 0; q < 4; ++q) {
      float v2 = acc[q] + bval;
      v2 = (G == 2) ? tanhf_(v2) : sigf(v2);
      gbuf[G][rf * 16 + ((lane >> 4) << 2) + q][lane & 15] = v2;
    }
    __syncthreads();

    {
      int row = tid >> 4, col = tid & 15;
      float iv = gbuf[0][row][col], fv = gbuf[1][row][col];
      float gv = gbuf[2][row][col], ov = gbuf[3][row][col];
      float cc = fv * cbuf[row][col] + iv * gv;
      cbuf[row][col] = cc;
      float hh = ov * tanhf_(cc);
      hbuf[row][col] = hh;
      int b = g * ROWS + row;
      if (l == 1) out[((size_t)b * kT + t) * kH + j * 16 + col] = hh;
      if (t == kT - 1) {
        size_t hb = (size_t)kB * kT * kH;
        out[hb + ((size_t)(l * 2 + 0) * kB + b) * kH + j * 16 + col] = hh;
        out[hb + ((size_t)(l * 2 + 1) * kB + b) * kH + j * 16 + col] = cc;
      }
    }
    __syncthreads();

    if (tid < 256) {
      int row = tid >> 3, cp = tid & 7;
      uint32_t pkv = (uint32_t)f2bf(hbuf[row][2 * cp]) | ((uint32_t)f2bf(hbuf[row][2 * cp + 1]) << 16);
      uint32_t* dst = (uint32_t*)(rrec + (size_t)((t + 1) % Rrec) * SLOT_ELEMS
                                  + (size_t)(g * ROWS + row) * kH + j * 16 + 2 * cp);
      __hip_atomic_store(dst, pkv, __ATOMIC_RELAXED, __HIP_MEMORY_SCOPE_AGENT);
    }
    asm volatile("s_waitcnt vmcnt(0)" ::: "memory");
    __syncthreads();
    if (tid == 0)
      __hip_atomic_fetch_add(&mycnt[t], 1, __ATOMIC_RELAXED, __HIP_MEMORY_SCOPE_AGENT);
  }
}

extern "C" void kernel_launch(void* const* d_in, const int* in_sizes, int n_in,
                              void* d_out, int out_size, void* d_ws, size_t ws_size,
                              hipStream_t stream) {
  const float* x  = (const float*)d_in[0];
  const float* hd = (const float*)d_in[1];
  const float* W  = (const float*)d_in[2];
  const float* b  = (const float*)d_in[3];
  float* out = (float*)d_out;

  char* ws = (char*)d_ws;
  ushort* wimg = (ushort*)ws;
  uint8_t* flags = (uint8_t*)(ws + WIMG_BYTES);                // 1 MB
  int* cnt  = (int*)(ws + WIMG_BYTES + FLAG_TOTAL);            // 16 KB (fallback)
  int* cons = (int*)(ws + WIMG_BYTES + FLAG_TOTAL + 16384);    // 8 KB  (fallback)
  size_t ringoff = WIMG_BYTES + FLAG_TOTAL + 32768;
  size_t avail = ws_size > ringoff ? ws_size - ringoff : 0;
  long rmax = (long)(avail / (2 * SLOT_ELEMS * 2));
  int R = (rmax >= RFULL) ? RFULL : (rmax >= 16 ? 16 : (rmax >= 2 ? (int)rmax : 2));
  ushort* ring0 = (ushort*)(ws + ringoff);
  ushort* ring1 = ring0 + (size_t)R * SLOT_ELEMS;

  prep_w<<<(int)(WIMG_ELEMS / 256), 256, 0, stream>>>(W, wimg);
  prep_init<<<(2 * kB * kH) / 256, 256, 0, stream>>>(hd, ring0, ring1);
  if (R == RFULL) {
    hipMemsetAsync(flags, 0, FLAG_TOTAL, stream);
    lstm_flag<<<256, NTHREADS, 0, stream>>>(x, hd, b, wimg, ring0, ring1, flags, out);
  } else {
    hipMemsetAsync(ws + WIMG_BYTES + FLAG_TOTAL, 0, 32768, stream);
    lstm_main<false><<<256, NTHREADS, 0, stream>>>(x, hd, b, wimg, ring0, ring1, cnt, cons, out, R, R);
  }
}

// Round 3
// 2144.758 us; speedup vs baseline: 2.0019x; 2.0019x over previous
//
#include <hip/hip_runtime.h>
#include <stdint.h>

typedef __attribute__((ext_vector_type(4))) int   i32x4;
typedef __attribute__((ext_vector_type(8))) short bf16x8;
typedef __attribute__((ext_vector_type(4))) float f32x4;

#define DEV static __device__ __forceinline__

constexpr int  kB = 128, kT = 512, kD = 512, kH = 512;
constexpr int  kGC = 2048;               // 4*H
constexpr int  ROWS = 32;                // batch rows per block
constexpr int  NG = 4;                   // batch groups
constexpr int  NJ = 32;                  // column-slice blocks per cluster
constexpr int  NTHREADS = 512;
constexpr size_t SLOT_ELEMS = (size_t)kB * kH;            // bf16 elems per ring slot -> 128 KB
constexpr size_t WIMG_ELEMS = (size_t)2 * NJ * 4 * 32 * 512; // 4,194,304 bf16
constexpr size_t WIMG_BYTES = WIMG_ELEMS * 2;             // 8 MB
constexpr int  RFULL = kT + 1;           // 513
constexpr int  FLAG_STRIDE = 128;        // one cacheline per (l,g,t); bytes 0..31 used (one per j)
constexpr size_t FLAG_TOTAL = (size_t)2 * NG * kT * FLAG_STRIDE; // 512 KB

DEV ushort f2bf(float f) {
  uint32_t u = __float_as_uint(f);
  u += 0x7fff + ((u >> 16) & 1);        // round-to-nearest-even
  return (ushort)(u >> 16);
}
DEV int pk2(float a, float b) { return (int)((uint32_t)f2bf(a) | ((uint32_t)f2bf(b) << 16)); }
DEV float sigf(float v)  { return 1.f / (1.f + __expf(-v)); }
DEV float tanhf_(float v){ return 1.f - 2.f / (__expf(2.f * v) + 1.f); }

DEV uint64_t ald64(const uint64_t* p) {
  return __hip_atomic_load(p, __ATOMIC_RELAXED, __HIP_MEMORY_SCOPE_AGENT);
}

// Wave-uniform broadcast poll: ALL lanes load the SAME 32-byte flag region
// (4 x u64, one cacheline). Same-address lanes coalesce to one broadcast
// request -> as cheap as a single-lane poll, but no tid0->barrier hop.
DEV void poll32(const uint8_t* fb) {
  const uint64_t* p = reinterpret_cast<const uint64_t*>(fb);
  constexpr uint64_t ONE = 0x0101010101010101ull;
  for (;;) {
    uint64_t a = ald64(p) & ald64(p + 1) & ald64(p + 2) & ald64(p + 3);
    if (a == ONE) return;
    __builtin_amdgcn_s_sleep(1);
  }
}

// ---- prep: W (L,1024,2048) fp32 -> bf16 MFMA B-fragment image ----
__global__ void prep_w(const float* __restrict__ W, ushort* __restrict__ wimg) {
  uint32_t idx = blockIdx.x * 256u + threadIdx.x;
  int e = idx & 7, lane = (idx >> 3) & 63, ks = (idx >> 9) & 31;
  int G = (idx >> 14) & 3, j = (idx >> 16) & 31, l = (idx >> 21) & 1;
  int k = ks * 32 + ((lane >> 4) << 3) + e;
  int c = G * 512 + j * 16 + (lane & 15);
  wimg[idx] = f2bf(W[(size_t)l * 1024 * 2048 + (size_t)k * 2048 + c]);
}

// ---- prep: initial h (hiddens[l][0]) fp32 -> ring slot 0 bf16 ----
__global__ void prep_init(const float* __restrict__ hiddens, ushort* __restrict__ r0, ushort* __restrict__ r1) {
  uint32_t idx = blockIdx.x * 256u + threadIdx.x;   // 0 .. 2*65536-1
  int l = idx >> 16; uint32_t r = idx & 65535u;
  ushort v = f2bf(hiddens[(size_t)(l * 2 + 0) * 65536 + r]);
  (l ? r1 : r0)[r] = v;
}

// Bulk-stage 32 rows x 512 cols bf16 from a ring slot into a swizzled LDS half-tile.
// PLAIN vector loads (fast path) — validity guaranteed by a prior poll32.
DEV void stage_h(ushort* Ab, const ushort* rbase, int g, int tid) {
  #pragma unroll
  for (int p = 0; p < 4; ++p) {
    int o = (tid + p * NTHREADS) * 16, row = o >> 10, kb = o & 1023;
    i32x4 v = *reinterpret_cast<const i32x4*>(rbase + (size_t)(g * ROWS + row) * kH + (kb >> 1));
    *reinterpret_cast<i32x4*>(reinterpret_cast<char*>(Ab) + ((row * 1024 + kb) ^ ((row & 7) << 4))) = v;
  }
}

// ======================= BIG path: round-0 skeleton + surgical cuts =======================
__launch_bounds__(NTHREADS, 2)
__global__ void lstm_v3(const float* __restrict__ x, const float* __restrict__ hiddens,
                        const float* __restrict__ bias, const ushort* __restrict__ wimg,
                        ushort* __restrict__ ring0, ushort* __restrict__ ring1,
                        uint8_t* __restrict__ flags, float* __restrict__ out) {
  __shared__ ushort AbufX[ROWS * 512];    // 32 KB: input half (k=0..511)
  __shared__ ushort AbufH[ROWS * 512];    // 32 KB: recurrent half (k=512..1023)
  __shared__ float  gbuf[4][ROWS][17];    // activated gates (+1 pad kills 4-way write conflict)

  const int tid  = threadIdx.x;
  const int lane = tid & 63;
  const int wv   = tid >> 6;
  const int G    = wv & 3;                // gate strip
  const int rf   = wv >> 2;               // row-fragment (16 rows)
  const int j    = blockIdx.x & 31;       // column slice
  const int g    = (blockIdx.x >> 5) & 3; // batch group
  const int l    = blockIdx.x >> 7;       // layer

  __threadfence();  // entry agent fence: kill cross-replay stale cache lines

  // W slice resident in registers: 32 ksteps x 16B B-fragments
  i32x4 wr[32];
  {
    const ushort* base = wimg + (((size_t)(l * NJ + j) * 4 + G) * 32) * 512 + lane * 8;
    #pragma unroll
    for (int ks = 0; ks < 32; ++ks)
      wr[ks] = *reinterpret_cast<const i32x4*>(base + ks * 512);
  }
  const float bval = bias[l * kGC + G * 512 + j * 16 + (lane & 15)];
  const int urow = tid >> 4, ucol = tid & 15;        // c/h-update role
  float creg = hiddens[((size_t)(l * 2 + 1) * kB + (g * ROWS + urow)) * kH + j * 16 + ucol];

  ushort* rrec = l ? ring1 : ring0;
  uint8_t* myflags = flags + (size_t)(l * NG + g) * kT * FLAG_STRIDE;
  const uint8_t* xflags = flags + (size_t)g * kT * FLAG_STRIDE;  // layer-0 cluster (l==1 only)

  const int arow  = rf * 16 + (lane & 15);
  const int koff  = (lane >> 4) << 3;
  const int abase = arow * 1024;
  const int aswz  = (arow & 7) << 4;

  for (int t = 0; t < kT; ++t) {
    // ---------- phase X: stage input half -> AbufX ----------
    if (l == 1) {
      poll32(xflags + (size_t)t * FLAG_STRIDE);        // layer0 finished step t
      stage_h(AbufX, ring0 + (size_t)(t + 1) * SLOT_ELEMS, g, tid);
    } else {
      #pragma unroll
      for (int p = 0; p < 4; ++p) {
        int o = (tid + p * NTHREADS) * 16, row = o >> 10, kb = o & 1023;
        const float* src = x + ((size_t)(g * ROWS + row) * kT + t) * kD + (kb >> 1);
        f32x4 f0 = *reinterpret_cast<const f32x4*>(src);
        f32x4 f1 = *reinterpret_cast<const f32x4*>(src + 4);
        i32x4 v;
        v[0] = pk2(f0[0], f0[1]); v[1] = pk2(f0[2], f0[3]);
        v[2] = pk2(f1[0], f1[1]); v[3] = pk2(f1[2], f1[3]);
        *reinterpret_cast<i32x4*>(reinterpret_cast<char*>(AbufX) + ((row * 1024 + kb) ^ ((row & 7) << 4))) = v;
      }
    }
    __syncthreads();                                   // S1: AbufX ready

    // ---------- half 0 MFMA (overlaps peers' publish of h_{t-1}) ----------
    f32x4 acc = {};
    #pragma unroll
    for (int ks = 0; ks < 16; ++ks) {
      int off = (abase + ((ks * 32 + koff) << 1)) ^ aswz;
      i32x4 av = *reinterpret_cast<const i32x4*>(reinterpret_cast<const char*>(AbufX) + off);
      acc = __builtin_amdgcn_mfma_f32_16x16x32_bf16(
              *reinterpret_cast<bf16x8*>(&av), *reinterpret_cast<bf16x8*>(&wr[ks]), acc, 0, 0, 0);
    }

    // ---------- poll peers' h_{t-1}, then stage recurrent half -> AbufH ----------
    if (t > 0) poll32(myflags + (size_t)(t - 1) * FLAG_STRIDE);
    stage_h(AbufH, rrec + (size_t)t * SLOT_ELEMS, g, tid);
    __syncthreads();                                   // S2: AbufH ready

    // ---------- half 1 MFMA ----------
    #pragma unroll
    for (int ks = 0; ks < 16; ++ks) {
      int off = (abase + ((ks * 32 + koff) << 1)) ^ aswz;
      i32x4 av = *reinterpret_cast<const i32x4*>(reinterpret_cast<const char*>(AbufH) + off);
      acc = __builtin_amdgcn_mfma_f32_16x16x32_bf16(
              *reinterpret_cast<bf16x8*>(&av), *reinterpret_cast<bf16x8*>(&wr[16 + ks]), acc, 0, 0, 0);
    }

    // ---------- activation + gate exchange ----------
    #pragma unroll
    for (int q = 0; q < 4; ++q) {
      float v2 = acc[q] + bval;
      v2 = (G == 2) ? tanhf_(v2) : sigf(v2);
      gbuf[G][rf * 16 + ((lane >> 4) << 2) + q][lane & 15] = v2;  // C/D: row=(lane>>4)*4+q, col=lane&15
    }
    __syncthreads();                                   // S3: gates ready

    // ---------- c/h update + publish ----------
    float hh;
    {
      float iv = gbuf[0][urow][ucol], fv = gbuf[1][urow][ucol];
      float gv = gbuf[2][urow][ucol], ov = gbuf[3][urow][ucol];
      creg = fv * creg + iv * gv;
      hh = ov * tanhf_(creg);
      uint32_t me    = f2bf(hh);
      uint32_t other = (uint32_t)__shfl_xor((int)me, 1);  // partner col^1, same wave
      if (!(ucol & 1)) {
        uint32_t pkv = me | (other << 16);
        uint32_t* dst = (uint32_t*)(rrec + (size_t)(t + 1) * SLOT_ELEMS
                                    + (size_t)(g * ROWS + urow) * kH + j * 16 + ucol);
        __hip_atomic_store(dst, pkv, __ATOMIC_RELAXED, __HIP_MEMORY_SCOPE_AGENT);
      }
    }
    asm volatile("s_waitcnt vmcnt(0)" ::: "memory");   // drain own publish stores
    __syncthreads();                                   // S_p: all waves' publishes drained
    if (tid == 0)
      __hip_atomic_store(myflags + (size_t)t * FLAG_STRIDE + j, (uint8_t)1,
                         __ATOMIC_RELAXED, __HIP_MEMORY_SCOPE_AGENT);

    // bulk output writes AFTER the flag: they never delay the signal
    {
      int b = g * ROWS + urow;
      if (l == 1) out[((size_t)b * kT + t) * kH + j * 16 + ucol] = hh;
      if (t == kT - 1) {
        size_t hb = (size_t)kB * kT * kH;
        out[hb + ((size_t)(l * 2 + 0) * kB + b) * kH + j * 16 + ucol] = hh;
        out[hb + ((size_t)(l * 2 + 1) * kB + b) * kH + j * 16 + ucol] = creg;
      }
    }
  }
}

// ======================= small-workspace fallback (round-0 proven path) =======================

template<bool BIG>
DEV void stage_ring(ushort* Abuf_, const ushort* rbase, int g, int tid) {
  #pragma unroll
  for (int p = 0; p < 4; ++p) {
    int o = (tid + p * NTHREADS) * 16;
    int row = o >> 10, kb = o & 1023;
    const ushort* src = rbase + (size_t)(g * ROWS + row) * kH + (kb >> 1);
    i32x4 v;
    if (BIG) {
      v = *reinterpret_cast<const i32x4*>(src);
    } else {
      uint64_t lo = __hip_atomic_load((const uint64_t*)src,       __ATOMIC_RELAXED, __HIP_MEMORY_SCOPE_AGENT);
      uint64_t hi = __hip_atomic_load((const uint64_t*)(src + 4), __ATOMIC_RELAXED, __HIP_MEMORY_SCOPE_AGENT);
      v[0] = (int)(uint32_t)lo; v[1] = (int)(uint32_t)(lo >> 32);
      v[2] = (int)(uint32_t)hi; v[3] = (int)(uint32_t)(hi >> 32);
    }
    *reinterpret_cast<i32x4*>(reinterpret_cast<char*>(Abuf_) + ((row * 1024 + kb) ^ ((row & 7) << 4))) = v;
  }
}

template<bool BIG>
__launch_bounds__(NTHREADS, 2)
__global__ void lstm_main(const float* __restrict__ x, const float* __restrict__ hiddens,
                          const float* __restrict__ bias, const ushort* __restrict__ wimg,
                          ushort* __restrict__ ring0, ushort* __restrict__ ring1,
                          int* __restrict__ cnt, int* __restrict__ cons0,
                          float* __restrict__ out, int R0, int R1) {
  __shared__ ushort Abuf[ROWS * 512];
  __shared__ float  gbuf[4][ROWS][16];
  __shared__ float  cbuf[ROWS][16];
  __shared__ float  hbuf[ROWS][16];

  const int tid  = threadIdx.x;
  const int lane = tid & 63;
  const int wv   = tid >> 6;
  const int G    = wv & 3;
  const int rf   = wv >> 2;
  const int j    = blockIdx.x & 31;
  const int g    = (blockIdx.x >> 5) & 3;
  const int l    = blockIdx.x >> 7;

  __threadfence();

  i32x4 wr[32];
  {
    const ushort* base = wimg + (((size_t)(l * NJ + j) * 4 + G) * 32) * 512 + lane * 8;
    #pragma unroll
    for (int ks = 0; ks < 32; ++ks)
      wr[ks] = *reinterpret_cast<const i32x4*>(base + ks * 512);
  }
  const float bval = bias[l * kGC + G * 512 + j * 16 + (lane & 15)];
  {
    int row = tid >> 4, col = tid & 15;
    cbuf[row][col] = hiddens[((size_t)(l * 2 + 1) * kB + (g * ROWS + row)) * kH + j * 16 + col];
  }
  int* mycnt = cnt + (l * NG + g) * kT;
  int* c0cnt = cnt + g * kT;
  ushort* rrec = l ? ring1 : ring0;
  const int Rrec = l ? R1 : R0;

  const int arow  = rf * 16 + (lane & 15);
  const int koff  = (lane >> 4) << 3;
  const int abase = arow * 1024;
  const int aswz  = (arow & 7) << 4;

  __syncthreads();

  for (int t = 0; t < kT; ++t) {
    if (l == 1) {
      if (tid == 0) {
        while (__hip_atomic_load(&c0cnt[t], __ATOMIC_RELAXED, __HIP_MEMORY_SCOPE_AGENT) < NJ)
          __builtin_amdgcn_s_sleep(2);
      }
      __syncthreads();
      stage_ring<BIG>(Abuf, ring0 + (size_t)((t + 1) % R0) * SLOT_ELEMS, g, tid);
    } else {
      #pragma unroll
      for (int p = 0; p < 4; ++p) {
        int o = (tid + p * NTHREADS) * 16;
        int row = o >> 10, kb = o & 1023;
        const float* src = x + ((size_t)(g * ROWS + row) * kT + t) * kD + (kb >> 1);
        f32x4 f0 = *reinterpret_cast<const f32x4*>(src);
        f32x4 f1 = *reinterpret_cast<const f32x4*>(src + 4);
        i32x4 v;
        v[0] = pk2(f0[0], f0[1]); v[1] = pk2(f0[2], f0[3]);
        v[2] = pk2(f1[0], f1[1]); v[3] = pk2(f1[2], f1[3]);
        *reinterpret_cast<i32x4*>(reinterpret_cast<char*>(Abuf) + ((row * 1024 + kb) ^ ((row & 7) << 4))) = v;
      }
    }
    __syncthreads();
    if (!BIG && l == 1 && tid == 0)
      __hip_atomic_fetch_add(&cons0[g * kT + t], 1, __ATOMIC_RELAXED, __HIP_MEMORY_SCOPE_AGENT);

    f32x4 acc = {};
    #pragma unroll
    for (int ks = 0; ks < 16; ++ks) {
      int off = (abase + ((ks * 32 + koff) << 1)) ^ aswz;
      i32x4 av = *reinterpret_cast<const i32x4*>(reinterpret_cast<const char*>(Abuf) + off);
      acc = __builtin_amdgcn_mfma_f32_16x16x32_bf16(
              *reinterpret_cast<bf16x8*>(&av), *reinterpret_cast<bf16x8*>(&wr[ks]), acc, 0, 0, 0);
    }
    __syncthreads();

    if (t > 0) {
      if (tid == 0) {
        while (__hip_atomic_load(&mycnt[t - 1], __ATOMIC_RELAXED, __HIP_MEMORY_SCOPE_AGENT) < NJ)
          __builtin_amdgcn_s_sleep(2);
        if (!BIG && l == 0 && t >= R0) {
          while (__hip_atomic_load(&cons0[g * kT + (t - R0)], __ATOMIC_RELAXED, __HIP_MEMORY_SCOPE_AGENT) < NJ)
            __builtin_amdgcn_s_sleep(2);
        }
      }
      __syncthreads();
    }
    stage_ring<BIG>(Abuf, rrec + (size_t)(t % Rrec) * SLOT_ELEMS, g, tid);
    __syncthreads();

    #pragma unroll
    for (int ks = 0; ks < 16; ++ks) {
      int off = (abase + ((ks * 32 + koff) << 1)) ^ aswz;
      i32x4 av = *reinterpret_cast<const i32x4*>(reinterpret_cast<const char*>(Abuf) + off);
      acc = __builtin_amdgcn_mfma_f32_16x16x32_bf16(
              *reinterpret_cast<bf16x8*>(&av), *reinterpret_cast<bf16x8*>(&wr[16 + ks]), acc, 0, 0, 0);
    }

    #pragma unroll
    for (int q = 0; q < 4; ++q) {
      float v2 = acc[q] + bval;
      v2 = (G == 2) ? tanhf_(v2) : sigf(v2);
      gbuf[G][rf * 16 + ((lane >> 4) << 2) + q][lane & 15] = v2;
    }
    __syncthreads();

    {
      int row = tid >> 4, col = tid & 15;
      float iv = gbuf[0][row][col], fv = gbuf[1][row][col];
      float gv = gbuf[2][row][col], ov = gbuf[3][row][col];
      float cc = fv * cbuf[row][col] + iv * gv;
      cbuf[row][col] = cc;
      float hh = ov * tanhf_(cc);
      hbuf[row][col] = hh;
      int b = g * ROWS + row;
      if (l == 1) out[((size_t)b * kT + t) * kH + j * 16 + col] = hh;
      if (t == kT - 1) {
        size_t hb = (size_t)kB * kT * kH;
        out[hb + ((size_t)(l * 2 + 0) * kB + b) * kH + j * 16 + col] = hh;
        out[hb + ((size_t)(l * 2 + 1) * kB + b) * kH + j * 16 + col] = cc;
      }
    }
    __syncthreads();

    if (tid < 256) {
      int row = tid >> 3, cp = tid & 7;
      uint32_t pkv = (uint32_t)f2bf(hbuf[row][2 * cp]) | ((uint32_t)f2bf(hbuf[row][2 * cp + 1]) << 16);
      uint32_t* dst = (uint32_t*)(rrec + (size_t)((t + 1) % Rrec) * SLOT_ELEMS
                                  + (size_t)(g * ROWS + row) * kH + j * 16 + 2 * cp);
      __hip_atomic_store(dst, pkv, __ATOMIC_RELAXED, __HIP_MEMORY_SCOPE_AGENT);
    }
    asm volatile("s_waitcnt vmcnt(0)" ::: "memory");
    __syncthreads();
    if (tid == 0)
      __hip_atomic_fetch_add(&mycnt[t], 1, __ATOMIC_RELAXED, __HIP_MEMORY_SCOPE_AGENT);
  }
}

extern "C" void kernel_launch(void* const* d_in, const int* in_sizes, int n_in,
                              void* d_out, int out_size, void* d_ws, size_t ws_size,
                              hipStream_t stream) {
  const float* x  = (const float*)d_in[0];
  const float* hd = (const float*)d_in[1];
  const float* W  = (const float*)d_in[2];
  const float* b  = (const float*)d_in[3];
  float* out = (float*)d_out;

  char* ws = (char*)d_ws;
  ushort* wimg = (ushort*)ws;
  uint8_t* flags = (uint8_t*)(ws + WIMG_BYTES);                // 512 KB
  int* cnt  = (int*)(ws + WIMG_BYTES + FLAG_TOTAL);            // 16 KB (fallback)
  int* cons = (int*)(ws + WIMG_BYTES + FLAG_TOTAL + 16384);    // 8 KB  (fallback)
  size_t ringoff = WIMG_BYTES + FLAG_TOTAL + 32768;
  size_t avail = ws_size > ringoff ? ws_size - ringoff : 0;
  long rmax = (long)(avail / (2 * SLOT_ELEMS * 2));
  int R = (rmax >= RFULL) ? RFULL : (rmax >= 16 ? 16 : (rmax >= 2 ? (int)rmax : 2));
  ushort* ring0 = (ushort*)(ws + ringoff);
  ushort* ring1 = ring0 + (size_t)R * SLOT_ELEMS;

  prep_w<<<(int)(WIMG_ELEMS / 256), 256, 0, stream>>>(W, wimg);
  prep_init<<<(2 * kB * kH) / 256, 256, 0, stream>>>(hd, ring0, ring1);
  if (R == RFULL) {
    hipMemsetAsync(flags, 0, FLAG_TOTAL, stream);
    lstm_v3<<<256, NTHREADS, 0, stream>>>(x, hd, b, wimg, ring0, ring1, flags, out);
  } else {
    hipMemsetAsync(ws + WIMG_BYTES + FLAG_TOTAL, 0, 32768, stream);
    lstm_main<false><<<256, NTHREADS, 0, stream>>>(x, hd, b, wimg, ring0, ring1, cnt, cons, out, R, R);
  }
}